// Round 2
// baseline (554.905 us; speedup 1.0000x reference)
//
#include <hip/hip_runtime.h>
#include <math.h>

typedef unsigned short u16;
typedef __attribute__((ext_vector_type(8))) short short8;
typedef __attribute__((ext_vector_type(4))) float f32x4;

#define AS1C(p) ((const __attribute__((address_space(1))) void*)(p))
#define AS3(p)  ((__attribute__((address_space(3))) void*)(p))

static __device__ __forceinline__ float b2f(u16 h) {
    union { unsigned u; float f; } c; c.u = ((unsigned)h) << 16; return c.f;
}
static __device__ __forceinline__ u16 f2b(float f) {
    union { float f; unsigned u; } c; c.f = f;
    unsigned r = c.u + 0x7FFFu + ((c.u >> 16) & 1u);
    return (u16)(r >> 16);
}

// Epilogue modes
#define EP_NONE     0
#define EP_RELU     1
#define EP_SIGMOID  2
#define EP_TANH_MUL 3   // out = tanh(acc+bias) * auxf[R,C]
#define EP_TANH_ADD 4   // out = auxf[R,C] + tanh(acc+bias)
#define EP_DIAG     5   // out = acc; if (R==C) += 0.9*tanh(auxf[R])

// C[M,N] = A[M,K] @ W[N,K]^T (+bias[N]) with epilogue.
// A bf16 row-stride lda, W bf16 dense [N,K]. bias/auxf fp32.
// outb bf16 row-stride ldd; if BOTH also outf fp32 dense [M,N].
// M%128==0, N%128==0, K%64==0, lda%8==0. 256 threads, 4 waves 2x2, wave=64x64.
template<int EP, bool BOTH>
__global__ __launch_bounds__(256)
void gemm_bt(const u16* __restrict__ A, int lda, const u16* __restrict__ W,
             const float* __restrict__ bias, const float* __restrict__ auxf,
             u16* __restrict__ outb, int ldd, float* __restrict__ outf,
             int M, int N, int K)
{
    __shared__ __align__(16) u16 As[128 * 64];
    __shared__ __align__(16) u16 Bs[128 * 64];

    const int tid  = threadIdx.x;
    const int nbm  = M >> 7;
    const int bm   = (int)blockIdx.x % nbm;
    const int bn   = (int)blockIdx.x / nbm;
    const int lane = tid & 63;
    const int wave = tid >> 6;
    const int wr   = wave >> 1;
    const int wc   = wave & 1;

    // staging: thread covers rows srow + i*32 (i=0..3), 8 bf16 at col scol
    const int srow = tid >> 3;          // 0..31
    const int scol = (tid & 7) * 8;     // 0..56

    const u16* Ab = A + (size_t)(bm * 128 + srow) * lda + scol;
    const u16* Wb = W + (size_t)(bn * 128 + srow) * K + scol;
    u16* Asl = As + srow * 64 + scol;
    u16* Bsl = Bs + srow * 64 + scol;

    f32x4 acc[4][4];
#pragma unroll
    for (int m = 0; m < 4; ++m)
#pragma unroll
        for (int n = 0; n < 4; ++n) acc[m][n] = (f32x4){0.f, 0.f, 0.f, 0.f};

    const u16* ArdBase = As + ((wr * 64) + (lane & 15)) * 64 + (lane >> 4) * 8;
    const u16* BrdBase = Bs + ((wc * 64) + (lane & 15)) * 64 + (lane >> 4) * 8;

    for (int k0 = 0; k0 < K; k0 += 64) {
#pragma unroll
        for (int i = 0; i < 4; ++i) {
            __builtin_amdgcn_global_load_lds(AS1C(Ab + (size_t)(i * 32) * lda + k0),
                                             AS3(Asl + i * 32 * 64), 16, 0, 0);
            __builtin_amdgcn_global_load_lds(AS1C(Wb + (size_t)(i * 32) * K + k0),
                                             AS3(Bsl + i * 32 * 64), 16, 0, 0);
        }
        __syncthreads();
#pragma unroll
        for (int kk = 0; kk < 64; kk += 32) {
            short8 a[4], b[4];
#pragma unroll
            for (int m = 0; m < 4; ++m) a[m] = *(const short8*)(ArdBase + m * 16 * 64 + kk);
#pragma unroll
            for (int n = 0; n < 4; ++n) b[n] = *(const short8*)(BrdBase + n * 16 * 64 + kk);
#pragma unroll
            for (int m = 0; m < 4; ++m)
#pragma unroll
                for (int n = 0; n < 4; ++n)
                    acc[m][n] = __builtin_amdgcn_mfma_f32_16x16x32_bf16(a[m], b[n], acc[m][n], 0, 0, 0);
        }
        __syncthreads();
    }

    // epilogue: D layout col=lane&15, row=(lane>>4)*4+j
    const int rbase = bm * 128 + wr * 64 + (lane >> 4) * 4;
    const int cbase = bn * 128 + wc * 64 + (lane & 15);
#pragma unroll
    for (int n = 0; n < 4; ++n) {
        const int C = cbase + n * 16;
        const float bv = bias ? bias[C] : 0.f;
#pragma unroll
        for (int m = 0; m < 4; ++m) {
            const int R0 = rbase + m * 16;
#pragma unroll
            for (int j = 0; j < 4; ++j) {
                const int R = R0 + j;
                float v = acc[m][n][j] + bv;
                if constexpr (EP == EP_RELU)          v = fmaxf(v, 0.f);
                else if constexpr (EP == EP_SIGMOID)  v = 1.f / (1.f + expf(-v));
                else if constexpr (EP == EP_TANH_MUL) v = tanhf(v) * auxf[(size_t)R * N + C];
                else if constexpr (EP == EP_TANH_ADD) v = auxf[(size_t)R * N + C] + tanhf(v);
                else if constexpr (EP == EP_DIAG)     { if (R == C) v += 0.9f * tanhf(auxf[R]); }
                outb[(size_t)R * ldd + C] = f2b(v);
                if constexpr (BOTH) outf[(size_t)R * N + C] = v;
            }
        }
    }
}

// In-place LayerNorm over D=1024 bf16 (+optional ReLU). gam/bet fp32.
template<bool RELU>
__global__ __launch_bounds__(256)
void ln1024(u16* __restrict__ X, const float* __restrict__ gam, const float* __restrict__ bet)
{
    const int row = blockIdx.x;
    u16* xp = X + (size_t)row * 1024 + threadIdx.x * 4;
    u16 loc[4];
    *(uint2*)loc = *(const uint2*)xp;
    float x0 = b2f(loc[0]), x1 = b2f(loc[1]), x2 = b2f(loc[2]), x3 = b2f(loc[3]);
    float s = x0 + x1 + x2 + x3;
    float q = x0 * x0 + x1 * x1 + x2 * x2 + x3 * x3;
#pragma unroll
    for (int off = 32; off; off >>= 1) { s += __shfl_xor(s, off); q += __shfl_xor(q, off); }
    __shared__ float sm[8];
    const int wave = threadIdx.x >> 6, lane = threadIdx.x & 63;
    if (lane == 0) { sm[wave] = s; sm[4 + wave] = q; }
    __syncthreads();
    s = sm[0] + sm[1] + sm[2] + sm[3];
    q = sm[4] + sm[5] + sm[6] + sm[7];
    const float mean = s * (1.f / 1024.f);
    const float var  = q * (1.f / 1024.f) - mean * mean;
    const float inv  = rsqrtf(var + 1e-5f);
    const int cb = threadIdx.x * 4;
#pragma unroll
    for (int j = 0; j < 4; ++j) {
        float y = (b2f(loc[j]) - mean) * inv * gam[cb + j] + bet[cb + j];
        if (RELU) y = fmaxf(y, 0.f);
        loc[j] = f2b(y);
    }
    *(uint2*)xp = *(uint2*)loc;
}

// s_t = LN(s_prev + g*pm + (1-g)*wm) over D=1024. sp fp32, g/pm/wm bf16, out fp32.
__global__ __launch_bounds__(256)
void mix_ln(const float* __restrict__ sp, const u16* __restrict__ gt,
            const u16* __restrict__ pm, const u16* __restrict__ wm,
            const float* __restrict__ og, const float* __restrict__ ob,
            float* __restrict__ out)
{
    const int row = blockIdx.x;
    const size_t base = (size_t)row * 1024 + threadIdx.x * 4;
    float4 lsp = *(const float4*)(sp + base);
    u16 lg[4], lp[4], lw[4];
    *(uint2*)lg = *(const uint2*)(gt + base);
    *(uint2*)lp = *(const uint2*)(pm + base);
    *(uint2*)lw = *(const uint2*)(wm + base);
    float x[4];
    const float* lspp = (const float*)&lsp;
#pragma unroll
    for (int j = 0; j < 4; ++j) {
        float g = b2f(lg[j]);
        x[j] = lspp[j] + g * b2f(lp[j]) + (1.f - g) * b2f(lw[j]);
    }
    float s = x[0] + x[1] + x[2] + x[3];
    float q = x[0]*x[0] + x[1]*x[1] + x[2]*x[2] + x[3]*x[3];
#pragma unroll
    for (int off = 32; off; off >>= 1) { s += __shfl_xor(s, off); q += __shfl_xor(q, off); }
    __shared__ float sm[8];
    const int wave = threadIdx.x >> 6, lane = threadIdx.x & 63;
    if (lane == 0) { sm[wave] = s; sm[4 + wave] = q; }
    __syncthreads();
    s = sm[0] + sm[1] + sm[2] + sm[3];
    q = sm[4] + sm[5] + sm[6] + sm[7];
    const float mean = s * (1.f / 1024.f);
    const float var  = q * (1.f / 1024.f) - mean * mean;
    const float inv  = rsqrtf(var + 1e-5f);
    const int cb = threadIdx.x * 4;
    float4 o;
    float* op = (float*)&o;
#pragma unroll
    for (int j = 0; j < 4; ++j)
        op[j] = (x[j] - mean) * inv * og[cb + j] + ob[cb + j];
    *(float4*)(out + base) = o;
}

// fp32 -> bf16 bulk convert, 8 elems/thread
__global__ __launch_bounds__(256)
void cvt_f32_b16(const float* __restrict__ src, u16* __restrict__ dst, int n8)
{
    const int idx = blockIdx.x * 256 + threadIdx.x;
    if (idx >= n8) return;
    const float4 a = *(const float4*)(src + (size_t)idx * 8);
    const float4 b = *(const float4*)(src + (size_t)idx * 8 + 4);
    u16 o[8];
    const float* ap = (const float*)&a;
    const float* bp = (const float*)&b;
#pragma unroll
    for (int j = 0; j < 4; ++j) { o[j] = f2b(ap[j]); o[4 + j] = f2b(bp[j]); }
    *(uint4*)(dst + (size_t)idx * 8) = *(uint4*)o;
}

// fp32 src [rows, srcCols8*8] -> bf16 dst[:, off:off+cols] stride dstStride
__global__ __launch_bounds__(256)
void ccopy_f32(const float* __restrict__ src, u16* __restrict__ dst,
               int srcCols8, int dstStride, int dstOff)
{
    const int idx = blockIdx.x * 256 + threadIdx.x;
    const int r = idx / srcCols8;
    const int c = idx % srcCols8;
    const float4 a = *(const float4*)(src + ((size_t)r * srcCols8 + c) * 8);
    const float4 b = *(const float4*)(src + ((size_t)r * srcCols8 + c) * 8 + 4);
    u16 o[8];
    const float* ap = (const float*)&a;
    const float* bp = (const float*)&b;
#pragma unroll
    for (int j = 0; j < 4; ++j) { o[j] = f2b(ap[j]); o[4 + j] = f2b(bp[j]); }
    *(uint4*)(dst + (size_t)r * dstStride + dstOff + (size_t)c * 8) = *(uint4*)o;
}

// bf16 src -> bf16 dst column-copy
__global__ __launch_bounds__(256)
void ccopy_b16(const u16* __restrict__ src, u16* __restrict__ dst,
               int srcCols8, int dstStride, int dstOff)
{
    const int idx = blockIdx.x * 256 + threadIdx.x;
    const int r = idx / srcCols8;
    const int c = idx % srcCols8;
    const uint4 v = *(const uint4*)(src + ((size_t)r * srcCols8 + c) * 8);
    *(uint4*)(dst + (size_t)r * dstStride + dstOff + (size_t)c * 8) = v;
}

extern "C" void kernel_launch(void* const* d_in, const int* in_sizes, int n_in,
                              void* d_out, int out_size, void* d_ws, size_t ws_size,
                              hipStream_t stream)
{
    const float* s_prev = (const float*)d_in[0];
    const float* w_prev = (const float*)d_in[1];
    const float* p_prev = (const float*)d_in[2];
    const float* e_t    = (const float*)d_in[3];
    const float* c_t    = (const float*)d_in[4];
    const float* fw1    = (const float*)d_in[5];
    const float* fb1    = (const float*)d_in[6];
    const float* fln_g  = (const float*)d_in[7];
    const float* fln_b  = (const float*)d_in[8];
    const float* fw2    = (const float*)d_in[9];
    const float* fb2    = (const float*)d_in[10];
    const float* A_diag = (const float*)d_in[11];
    const float* A_U    = (const float*)d_in[12];
    const float* A_V    = (const float*)d_in[13];
    const float* amod_w = (const float*)d_in[14];
    const float* amod_b = (const float*)d_in[15];
    const float* bnet_w = (const float*)d_in[16];
    const float* bnet_b = (const float*)d_in[17];
    const float* pw1    = (const float*)d_in[18];
    const float* pb1    = (const float*)d_in[19];
    const float* pln_g  = (const float*)d_in[20];
    const float* pln_b  = (const float*)d_in[21];
    const float* pw2    = (const float*)d_in[22];
    const float* pb2    = (const float*)d_in[23];
    const float* pw3    = (const float*)d_in[24];
    const float* pb3    = (const float*)d_in[25];
    const float* gw     = (const float*)d_in[26];
    const float* gb     = (const float*)d_in[27];
    const float* uw     = (const float*)d_in[28];
    const float* up     = (const float*)d_in[29];
    const float* oln_g  = (const float*)d_in[30];
    const float* oln_b  = (const float*)d_in[31];

    float* out_s = (float*)d_out;                    // [8192,1024]
    float* out_w = out_s + (size_t)8192 * 1024;      // [8192,1024]
    float* out_p = out_w + (size_t)8192 * 1024;      // [8192,512]

    u16* ws = (u16*)d_ws;
    u16* FIN  = ws;                    // [8192,2560]; later PIN [8192,1536] at base
    u16* W_bf = ws + 12582912;         // [8192,1024] (tail of FIN region)
    u16* H    = ws + 20971520;         // [8192,1024]; later P_bf [8192,512]
    u16* P_bf = H;
    u16* Z    = ws + 29360128;         // [8192,512]
    u16* G    = ws + 33554432;         // [8192,1024]
    u16* ACAT = ws + 41943040;         // [8192,2048]; later PM/WM
    u16* PM   = ACAT;                  // [8192,1024]
    u16* WM   = ACAT + 8388608;        // [8192,1024]
    u16* WCAT = ws + 58720256;         // [1024,2048]
    u16* wb   = ws + 60817408;         // bf16 weights pool
    u16* fw1b  = wb;                   // 2,621,440
    u16* gwb   = wb + 2621440;         // 2,621,440
    u16* fw2b  = wb + 5242880;         // 524,288
    u16* amodb = wb + 5767168;         // 524,288
    u16* pw1b  = wb + 6291456;         // 1,572,864
    u16* pw2b  = wb + 7864320;         // 524,288
    u16* pw3b  = wb + 8388608;         // 262,144
    u16* uwb   = wb + 8650752;         // 1,048,576
    u16* upb   = wb + 9699328;         // 524,288
    u16* AUb   = wb + 10223616;        // 262,144
    u16* AVb   = wb + 10485760;        // 262,144  -> pool ends ws+71,565,312 (143.1 MB)

    const dim3 blk(256);
    auto cg = [](int n8) { return dim3((unsigned)((n8 + 255) / 256)); };
    auto g128 = [](int M, int N) { return dim3((unsigned)((M / 128) * (N / 128))); };

    // ---- weight conversions fp32->bf16
    cvt_f32_b16<<<cg(327680), blk, 0, stream>>>(fw1, fw1b, 327680);
    cvt_f32_b16<<<cg(327680), blk, 0, stream>>>(gw, gwb, 327680);
    cvt_f32_b16<<<cg(65536), blk, 0, stream>>>(fw2, fw2b, 65536);
    cvt_f32_b16<<<cg(65536), blk, 0, stream>>>(amod_w, amodb, 65536);
    cvt_f32_b16<<<cg(196608), blk, 0, stream>>>(pw1, pw1b, 196608);
    cvt_f32_b16<<<cg(65536), blk, 0, stream>>>(pw2, pw2b, 65536);
    cvt_f32_b16<<<cg(32768), blk, 0, stream>>>(pw3, pw3b, 32768);
    cvt_f32_b16<<<cg(131072), blk, 0, stream>>>(uw, uwb, 131072);
    cvt_f32_b16<<<cg(65536), blk, 0, stream>>>(up, upb, 65536);
    cvt_f32_b16<<<cg(32768), blk, 0, stream>>>(A_U, AUb, 32768);
    cvt_f32_b16<<<cg(32768), blk, 0, stream>>>(A_V, AVb, 32768);

    // ---- fin = [s_prev || e_t || c_t] bf16, stride 2560
    ccopy_f32<<<4096, blk, 0, stream>>>(s_prev, FIN, 128, 2560, 0);
    ccopy_f32<<<4096, blk, 0, stream>>>(e_t,    FIN, 128, 2560, 1024);
    ccopy_f32<<<2048, blk, 0, stream>>>(c_t,    FIN, 64,  2560, 2048);

    // ---- fusion MLP
    gemm_bt<EP_NONE, false><<<g128(8192, 1024), blk, 0, stream>>>(
        FIN, 2560, fw1b, fb1, nullptr, H, 1024, nullptr, 8192, 1024, 2560);
    ln1024<true><<<8192, blk, 0, stream>>>(H, fln_g, fln_b);
    gemm_bt<EP_NONE, false><<<g128(8192, 512), blk, 0, stream>>>(
        H, 1024, fw2b, fb2, nullptr, Z, 512, nullptr, 8192, 512, 1024);

    // ---- gate (reads FIN; must precede PIN overwrite)
    gemm_bt<EP_SIGMOID, false><<<g128(8192, 1024), blk, 0, stream>>>(
        FIN, 2560, gwb, gb, nullptr, G, 1024, nullptr, 8192, 1024, 2560);

    // ---- wave subsystem
    // X = tanh(c_t@amod^T+b) * w_prev  -> ACAT cols 0..1024
    gemm_bt<EP_TANH_MUL, false><<<g128(8192, 1024), blk, 0, stream>>>(
        FIN + 2048, 2560, amodb, amod_b, w_prev, ACAT, 2048, nullptr, 8192, 1024, 512);
    // A_base -> WCAT cols 0..1024
    gemm_bt<EP_DIAG, false><<<g128(1024, 1024), blk, 0, stream>>>(
        AUb, 256, AVb, nullptr, A_diag, WCAT, 2048, nullptr, 1024, 1024, 256);
    // ACAT cols 1024..1536 = c_t, 1536..2048 = z
    ccopy_f32<<<2048, blk, 0, stream>>>(c_t, ACAT, 64, 2048, 1024);
    ccopy_b16<<<2048, blk, 0, stream>>>(Z,   ACAT, 64, 2048, 1536);
    // WCAT cols 1024..2048 = bnet_w
    ccopy_f32<<<512, blk, 0, stream>>>(bnet_w, WCAT, 128, 2048, 1024);
    // w_t = ACAT @ WCAT^T + bnet_b  (bf16 W_bf + fp32 out_w)
    gemm_bt<EP_NONE, true><<<g128(8192, 1024), blk, 0, stream>>>(
        ACAT, 2048, WCAT, bnet_b, nullptr, W_bf, 1024, out_w, 8192, 1024, 2048);

    // ---- particle subsystem: PIN = [p_prev || z || c_t] at FIN base, stride 1536
    ccopy_f32<<<2048, blk, 0, stream>>>(p_prev, FIN, 64, 1536, 0);
    ccopy_b16<<<2048, blk, 0, stream>>>(Z,      FIN, 64, 1536, 512);
    ccopy_f32<<<2048, blk, 0, stream>>>(c_t,    FIN, 64, 1536, 1024);
    gemm_bt<EP_NONE, false><<<g128(8192, 1024), blk, 0, stream>>>(
        FIN, 1536, pw1b, pb1, nullptr, H, 1024, nullptr, 8192, 1024, 1536);
    ln1024<true><<<8192, blk, 0, stream>>>(H, pln_g, pln_b);
    gemm_bt<EP_RELU, false><<<g128(8192, 512), blk, 0, stream>>>(
        H, 1024, pw2b, pb2, nullptr, Z, 512, nullptr, 8192, 512, 1024);
    // p_t = p_prev + tanh(Z@pw3^T + pb3)  (bf16 P_bf + fp32 out_p)
    gemm_bt<EP_TANH_ADD, true><<<g128(8192, 512), blk, 0, stream>>>(
        Z, 512, pw3b, pb3, p_prev, P_bf, 512, out_p, 8192, 512, 512);

    // ---- mixing
    gemm_bt<EP_NONE, false><<<g128(8192, 1024), blk, 0, stream>>>(
        P_bf, 512, upb, nullptr, nullptr, PM, 1024, nullptr, 8192, 1024, 512);
    gemm_bt<EP_NONE, false><<<g128(8192, 1024), blk, 0, stream>>>(
        W_bf, 1024, uwb, nullptr, nullptr, WM, 1024, nullptr, 8192, 1024, 1024);
    mix_ln<<<8192, blk, 0, stream>>>(s_prev, G, PM, WM, oln_g, oln_b, out_s);
}

// Round 3
// 534.743 us; speedup vs baseline: 1.0377x; 1.0377x over previous
//
#include <hip/hip_runtime.h>
#include <math.h>

typedef unsigned short u16;
typedef __attribute__((ext_vector_type(8))) short short8;
typedef __attribute__((ext_vector_type(4))) float f32x4;

#define AS1C(p) ((const __attribute__((address_space(1))) void*)(p))
#define AS3(p)  ((__attribute__((address_space(3))) void*)(p))

static __device__ __forceinline__ float b2f(u16 h) {
    union { unsigned u; float f; } c; c.u = ((unsigned)h) << 16; return c.f;
}
static __device__ __forceinline__ u16 f2b(float f) {
    union { float f; unsigned u; } c; c.f = f;
    unsigned r = c.u + 0x7FFFu + ((c.u >> 16) & 1u);
    return (u16)(r >> 16);
}

// Epilogue modes (runtime)
#define EP_NONE     0
#define EP_RELU     1
#define EP_SIGMOID  2
#define EP_TANH_MUL 3   // out = tanh(acc+bias) * auxf[R,C]
#define EP_TANH_ADD 4   // out = auxf[R,C] + tanh(acc+bias)
#define EP_DIAG     5   // out = acc; if (R==C) += 0.9*tanh(auxf[R])

struct GDesc {
    const u16* A;       // [M, lda] bf16
    const u16* W;       // [N, K] bf16 dense
    const float* bias;  // [N] fp32 or null
    const float* auxf;  // fp32 aux (per-ep meaning) or null
    u16* outb;          // bf16 out, row stride ldd
    float* outf;        // fp32 out [M,N] dense, or null
    int lda, ldd, N, K, ep, nbm;
};

struct GArgs { GDesc d0, d1, d2; int s1, s2; };

// C = A @ W^T (+bias) with runtime epilogue. 128x128 tile, BK=64,
// 4 waves 2x2 (wave = 64x64), global_load_lds width-16 staging.
// Up to 3 horizontally-fused sub-GEMMs selected by block range.
__global__ __launch_bounds__(256)
void gemm_multi(GArgs ga)
{
    __shared__ __align__(16) u16 As[128 * 64];
    __shared__ __align__(16) u16 Bs[128 * 64];

    const int bid = (int)blockIdx.x;
    GDesc dd = (bid < ga.s1) ? ga.d0 : ((bid < ga.s2) ? ga.d1 : ga.d2);
    const int b = bid - ((bid < ga.s1) ? 0 : ((bid < ga.s2) ? ga.s1 : ga.s2));

    const int tid  = threadIdx.x;
    const int bm   = b % dd.nbm;
    const int bn   = b / dd.nbm;
    const int lane = tid & 63;
    const int wave = tid >> 6;
    const int wr   = wave >> 1;
    const int wc   = wave & 1;

    const int srow = tid >> 3;          // 0..31
    const int scol = (tid & 7) * 8;     // 0..56

    const int lda = dd.lda, K = dd.K, N = dd.N, ldd = dd.ldd;

    const u16* Ab = dd.A + (size_t)(bm * 128 + srow) * lda + scol;
    const u16* Wb = dd.W + (size_t)(bn * 128 + srow) * K + scol;
    u16* Asl = As + srow * 64 + scol;
    u16* Bsl = Bs + srow * 64 + scol;

    f32x4 acc[4][4];
#pragma unroll
    for (int m = 0; m < 4; ++m)
#pragma unroll
        for (int n = 0; n < 4; ++n) acc[m][n] = (f32x4){0.f, 0.f, 0.f, 0.f};

    const u16* ArdBase = As + ((wr * 64) + (lane & 15)) * 64 + (lane >> 4) * 8;
    const u16* BrdBase = Bs + ((wc * 64) + (lane & 15)) * 64 + (lane >> 4) * 8;

    for (int k0 = 0; k0 < K; k0 += 64) {
#pragma unroll
        for (int i = 0; i < 4; ++i) {
            __builtin_amdgcn_global_load_lds(AS1C(Ab + (size_t)(i * 32) * lda + k0),
                                             AS3(Asl + i * 32 * 64), 16, 0, 0);
            __builtin_amdgcn_global_load_lds(AS1C(Wb + (size_t)(i * 32) * K + k0),
                                             AS3(Bsl + i * 32 * 64), 16, 0, 0);
        }
        __syncthreads();
#pragma unroll
        for (int kk = 0; kk < 64; kk += 32) {
            short8 a[4], bb[4];
#pragma unroll
            for (int m = 0; m < 4; ++m) a[m] = *(const short8*)(ArdBase + m * 16 * 64 + kk);
#pragma unroll
            for (int n = 0; n < 4; ++n) bb[n] = *(const short8*)(BrdBase + n * 16 * 64 + kk);
#pragma unroll
            for (int m = 0; m < 4; ++m)
#pragma unroll
                for (int n = 0; n < 4; ++n)
                    acc[m][n] = __builtin_amdgcn_mfma_f32_16x16x32_bf16(a[m], bb[n], acc[m][n], 0, 0, 0);
        }
        __syncthreads();
    }

    // epilogue: D layout col=lane&15, row=(lane>>4)*4+j
    const int rbase = bm * 128 + wr * 64 + (lane >> 4) * 4;
    const int cbase = bn * 128 + wc * 64 + (lane & 15);
    const int ep = dd.ep;
#pragma unroll
    for (int n = 0; n < 4; ++n) {
        const int C = cbase + n * 16;
        const float bv = dd.bias ? dd.bias[C] : 0.f;
#pragma unroll
        for (int m = 0; m < 4; ++m) {
            const int R0 = rbase + m * 16;
#pragma unroll
            for (int j = 0; j < 4; ++j) {
                const int R = R0 + j;
                float v = acc[m][n][j] + bv;
                if (ep == EP_RELU)          v = fmaxf(v, 0.f);
                else if (ep == EP_SIGMOID)  v = 1.f / (1.f + expf(-v));
                else if (ep == EP_TANH_MUL) v = tanhf(v) * dd.auxf[(size_t)R * N + C];
                else if (ep == EP_TANH_ADD) v = dd.auxf[(size_t)R * N + C] + tanhf(v);
                else if (ep == EP_DIAG)     { if (R == C) v += 0.9f * tanhf(dd.auxf[R]); }
                dd.outb[(size_t)R * ldd + C] = f2b(v);
                if (dd.outf) dd.outf[(size_t)R * N + C] = v;
            }
        }
    }
}

// In-place LayerNorm over D=1024 bf16 (+optional ReLU). gam/bet fp32.
template<bool RELU>
__global__ __launch_bounds__(256)
void ln1024(u16* __restrict__ X, const float* __restrict__ gam, const float* __restrict__ bet)
{
    const int row = blockIdx.x;
    u16* xp = X + (size_t)row * 1024 + threadIdx.x * 4;
    u16 loc[4];
    *(uint2*)loc = *(const uint2*)xp;
    float x0 = b2f(loc[0]), x1 = b2f(loc[1]), x2 = b2f(loc[2]), x3 = b2f(loc[3]);
    float s = x0 + x1 + x2 + x3;
    float q = x0 * x0 + x1 * x1 + x2 * x2 + x3 * x3;
#pragma unroll
    for (int off = 32; off; off >>= 1) { s += __shfl_xor(s, off); q += __shfl_xor(q, off); }
    __shared__ float sm[8];
    const int wave = threadIdx.x >> 6, lane = threadIdx.x & 63;
    if (lane == 0) { sm[wave] = s; sm[4 + wave] = q; }
    __syncthreads();
    s = sm[0] + sm[1] + sm[2] + sm[3];
    q = sm[4] + sm[5] + sm[6] + sm[7];
    const float mean = s * (1.f / 1024.f);
    const float var  = q * (1.f / 1024.f) - mean * mean;
    const float inv  = rsqrtf(var + 1e-5f);
    const int cb = threadIdx.x * 4;
#pragma unroll
    for (int j = 0; j < 4; ++j) {
        float y = (b2f(loc[j]) - mean) * inv * gam[cb + j] + bet[cb + j];
        if (RELU) y = fmaxf(y, 0.f);
        loc[j] = f2b(y);
    }
    *(uint2*)xp = *(uint2*)loc;
}

// s_t = LN(s_prev + g*pm + (1-g)*wm) over D=1024. sp fp32, g/pm/wm bf16, out fp32.
__global__ __launch_bounds__(256)
void mix_ln(const float* __restrict__ sp, const u16* __restrict__ gt,
            const u16* __restrict__ pm, const u16* __restrict__ wm,
            const float* __restrict__ og, const float* __restrict__ ob,
            float* __restrict__ out)
{
    const int row = blockIdx.x;
    const size_t base = (size_t)row * 1024 + threadIdx.x * 4;
    float4 lsp = *(const float4*)(sp + base);
    u16 lg[4], lp[4], lw[4];
    *(uint2*)lg = *(const uint2*)(gt + base);
    *(uint2*)lp = *(const uint2*)(pm + base);
    *(uint2*)lw = *(const uint2*)(wm + base);
    float x[4];
    const float* lspp = (const float*)&lsp;
#pragma unroll
    for (int j = 0; j < 4; ++j) {
        float g = b2f(lg[j]);
        x[j] = lspp[j] + g * b2f(lp[j]) + (1.f - g) * b2f(lw[j]);
    }
    float s = x[0] + x[1] + x[2] + x[3];
    float q = x[0]*x[0] + x[1]*x[1] + x[2]*x[2] + x[3]*x[3];
#pragma unroll
    for (int off = 32; off; off >>= 1) { s += __shfl_xor(s, off); q += __shfl_xor(q, off); }
    __shared__ float sm[8];
    const int wave = threadIdx.x >> 6, lane = threadIdx.x & 63;
    if (lane == 0) { sm[wave] = s; sm[4 + wave] = q; }
    __syncthreads();
    s = sm[0] + sm[1] + sm[2] + sm[3];
    q = sm[4] + sm[5] + sm[6] + sm[7];
    const float mean = s * (1.f / 1024.f);
    const float var  = q * (1.f / 1024.f) - mean * mean;
    const float inv  = rsqrtf(var + 1e-5f);
    const int cb = threadIdx.x * 4;
    float4 o;
    float* op = (float*)&o;
#pragma unroll
    for (int j = 0; j < 4; ++j)
        op[j] = (x[j] - mean) * inv * og[cb + j] + ob[cb + j];
    *(float4*)(out + base) = o;
}

// Batched strided copy/convert: fp32->bf16 or bf16->bf16, 8 elems/thread.
struct CDesc { const void* src; u16* dst; int srcCols8; int dstStride; int dstOff; unsigned end; int isbf16; };
struct CArgs { CDesc d[16]; unsigned total; };

__global__ __launch_bounds__(256)
void multi_copy(CArgs ca)
{
    const unsigned idx = blockIdx.x * 256 + threadIdx.x;
    if (idx >= ca.total) return;
    int i = 0; unsigned start = 0;
    while (idx >= ca.d[i].end) { start = ca.d[i].end; ++i; }
    const CDesc cd = ca.d[i];
    const unsigned local = idx - start;
    const int r = local / cd.srcCols8;
    const int c = local % cd.srcCols8;
    u16 o[8];
    if (cd.isbf16) {
        *(uint4*)o = *(const uint4*)((const u16*)cd.src + ((size_t)r * cd.srcCols8 + c) * 8);
    } else {
        const float* s = (const float*)cd.src + ((size_t)r * cd.srcCols8 + c) * 8;
        const float4 a = *(const float4*)s;
        const float4 bq = *(const float4*)(s + 4);
        const float* ap = (const float*)&a;
        const float* bp = (const float*)&bq;
#pragma unroll
        for (int j = 0; j < 4; ++j) { o[j] = f2b(ap[j]); o[4 + j] = f2b(bp[j]); }
    }
    *(uint4*)(cd.dst + (size_t)r * cd.dstStride + cd.dstOff + (size_t)c * 8) = *(uint4*)o;
}

extern "C" void kernel_launch(void* const* d_in, const int* in_sizes, int n_in,
                              void* d_out, int out_size, void* d_ws, size_t ws_size,
                              hipStream_t stream)
{
    const float* s_prev = (const float*)d_in[0];
    const float* w_prev = (const float*)d_in[1];
    const float* p_prev = (const float*)d_in[2];
    const float* e_t    = (const float*)d_in[3];
    const float* c_t    = (const float*)d_in[4];
    const float* fw1    = (const float*)d_in[5];
    const float* fb1    = (const float*)d_in[6];
    const float* fln_g  = (const float*)d_in[7];
    const float* fln_b  = (const float*)d_in[8];
    const float* fw2    = (const float*)d_in[9];
    const float* fb2    = (const float*)d_in[10];
    const float* A_diag = (const float*)d_in[11];
    const float* A_U    = (const float*)d_in[12];
    const float* A_V    = (const float*)d_in[13];
    const float* amod_w = (const float*)d_in[14];
    const float* amod_b = (const float*)d_in[15];
    const float* bnet_w = (const float*)d_in[16];
    const float* bnet_b = (const float*)d_in[17];
    const float* pw1    = (const float*)d_in[18];
    const float* pb1    = (const float*)d_in[19];
    const float* pln_g  = (const float*)d_in[20];
    const float* pln_b  = (const float*)d_in[21];
    const float* pw2    = (const float*)d_in[22];
    const float* pb2    = (const float*)d_in[23];
    const float* pw3    = (const float*)d_in[24];
    const float* pb3    = (const float*)d_in[25];
    const float* gw     = (const float*)d_in[26];
    const float* gb     = (const float*)d_in[27];
    const float* uw     = (const float*)d_in[28];
    const float* up     = (const float*)d_in[29];
    const float* oln_g  = (const float*)d_in[30];
    const float* oln_b  = (const float*)d_in[31];

    float* out_s = (float*)d_out;                    // [8192,1024]
    float* out_w = out_s + (size_t)8192 * 1024;      // [8192,1024]
    float* out_p = out_w + (size_t)8192 * 1024;      // [8192,512]

    u16* ws = (u16*)d_ws;
    u16* FIN  = ws;                    // [8192,2560]; later PIN [8192,1536] at base
    u16* W_bf = ws + 12582912;         // [8192,1024] (tail of FIN region; written after amod reads FIN)
    u16* H    = ws + 20971520;         // [8192,1024]; later P1; later P_bf [8192,512]
    u16* P_bf = H;
    u16* Z    = ws + 29360128;         // [8192,512]
    u16* G    = ws + 33554432;         // [8192,1024]
    u16* ACAT = ws + 41943040;         // [8192,2048]; later PM/WM
    u16* PM   = ACAT;
    u16* WM   = ACAT + 8388608;
    u16* WCAT = ws + 58720256;         // [1024,2048]
    u16* wb   = ws + 60817408;         // bf16 weights pool
    u16* fw1b  = wb;
    u16* gwb   = wb + 2621440;
    u16* fw2b  = wb + 5242880;
    u16* amodb = wb + 5767168;
    u16* pw1b  = wb + 6291456;
    u16* pw2b  = wb + 7864320;
    u16* pw3b  = wb + 8388608;
    u16* uwb   = wb + 8650752;
    u16* upb   = wb + 9699328;
    u16* AUb   = wb + 10223616;
    u16* AVb   = wb + 10485760;        // pool ends ws+10,747,904 -> 143.1 MB total

    const dim3 blk(256);

    // ---------- batch 1: all weight cvts + FIN assembly + c_t->ACAT + bnet_w->WCAT
    {
        CArgs ca; unsigned cum = 0; int nd = 0;
        auto push = [&](const void* src, u16* dst, int cols8, int stride, int off,
                        int rows, int isbf) {
            cum += (unsigned)rows * cols8;
            ca.d[nd++] = CDesc{src, dst, cols8, stride, off, cum, isbf};
        };
        push(fw1,    fw1b,  320, 2560, 0,    1024, 0);
        push(gw,     gwb,   320, 2560, 0,    1024, 0);
        push(fw2,    fw2b,  128, 1024, 0,    512,  0);
        push(amod_w, amodb, 64,  512,  0,    1024, 0);
        push(pw1,    pw1b,  192, 1536, 0,    1024, 0);
        push(pw2,    pw2b,  128, 1024, 0,    512,  0);
        push(pw3,    pw3b,  64,  512,  0,    512,  0);
        push(uw,     uwb,   128, 1024, 0,    1024, 0);
        push(up,     upb,   64,  512,  0,    1024, 0);
        push(A_U,    AUb,   32,  256,  0,    1024, 0);
        push(A_V,    AVb,   32,  256,  0,    1024, 0);
        push(s_prev, FIN,   128, 2560, 0,    8192, 0);
        push(e_t,    FIN,   128, 2560, 1024, 8192, 0);
        push(c_t,    FIN,   64,  2560, 2048, 8192, 0);
        push(c_t,    ACAT,  64,  2048, 1024, 8192, 0);
        push(bnet_w, WCAT,  128, 2048, 1024, 1024, 0);
        ca.total = cum;
        multi_copy<<<dim3((cum + 255) / 256), blk, 0, stream>>>(ca);
    }

    // ---------- fused GEMM 1: fw1 (H) || gate (G), both A=FIN K=2560 -> 1024 blocks
    {
        GArgs ga;
        ga.d0 = GDesc{FIN, fw1b, fb1, nullptr, H, nullptr, 2560, 1024, 1024, 2560, EP_NONE,    64};
        ga.d1 = GDesc{FIN, gwb,  gb,  nullptr, G, nullptr, 2560, 1024, 1024, 2560, EP_SIGMOID, 64};
        ga.d2 = ga.d1; ga.s1 = 512; ga.s2 = 1024;
        gemm_multi<<<dim3(1024), blk, 0, stream>>>(ga);
    }
    ln1024<true><<<8192, blk, 0, stream>>>(H, fln_g, fln_b);

    // ---------- fused GEMM 2: fw2 (Z) || amod (X->ACAT) || A_base (WCAT) -> 832 blocks
    {
        GArgs ga;
        ga.d0 = GDesc{H,          fw2b,  fb2,    nullptr, Z,    nullptr, 1024, 512,  512,  1024, EP_NONE,     64};
        ga.d1 = GDesc{FIN + 2048, amodb, amod_b, w_prev,  ACAT, nullptr, 2560, 2048, 1024, 512,  EP_TANH_MUL, 64};
        ga.d2 = GDesc{AUb,        AVb,   nullptr, A_diag, WCAT, nullptr, 256,  2048, 1024, 256,  EP_DIAG,     8};
        ga.s1 = 256; ga.s2 = 768;
        gemm_multi<<<dim3(832), blk, 0, stream>>>(ga);
    }

    // ---------- batch 2: PIN = [p_prev || z || c_t] at FIN base; Z -> ACAT col 1536
    {
        CArgs ca; unsigned cum = 0; int nd = 0;
        auto push = [&](const void* src, u16* dst, int cols8, int stride, int off,
                        int rows, int isbf) {
            cum += (unsigned)rows * cols8;
            ca.d[nd++] = CDesc{src, dst, cols8, stride, off, cum, isbf};
        };
        push(p_prev, FIN,  64, 1536, 0,    8192, 0);
        push(Z,      FIN,  64, 1536, 512,  8192, 1);
        push(c_t,    FIN,  64, 1536, 1024, 8192, 0);
        push(Z,      ACAT, 64, 2048, 1536, 8192, 1);
        ca.total = cum;
        multi_copy<<<dim3((cum + 255) / 256), blk, 0, stream>>>(ca);
    }

    // ---------- fused GEMM 3: w_t (ACAT@WCAT^T -> W_bf + out_w) || pw1 (PIN -> H) -> 1024 blocks
    {
        GArgs ga;
        ga.d0 = GDesc{ACAT, WCAT, bnet_b, nullptr, W_bf, out_w, 2048, 1024, 1024, 2048, EP_NONE, 64};
        ga.d1 = GDesc{FIN,  pw1b, pb1,    nullptr, H,    nullptr, 1536, 1024, 1024, 1536, EP_NONE, 64};
        ga.d2 = ga.d1; ga.s1 = 512; ga.s2 = 1024;
        gemm_multi<<<dim3(1024), blk, 0, stream>>>(ga);
    }
    ln1024<true><<<8192, blk, 0, stream>>>(H, pln_g, pln_b);

    // ---------- fused GEMM 4: pw2 (H -> Z, relu) || uw (W_bf -> WM) -> 768 blocks
    {
        GArgs ga;
        ga.d0 = GDesc{H,    pw2b, pb2,    nullptr, Z,  nullptr, 1024, 512,  512,  1024, EP_RELU, 64};
        ga.d1 = GDesc{W_bf, uwb,  nullptr, nullptr, WM, nullptr, 1024, 1024, 1024, 1024, EP_NONE, 64};
        ga.d2 = ga.d1; ga.s1 = 256; ga.s2 = 768;
        gemm_multi<<<dim3(768), blk, 0, stream>>>(ga);
    }

    // ---------- pw3: p_t = p_prev + tanh(Z@pw3^T + pb3) -> P_bf + out_p
    {
        GArgs ga;
        ga.d0 = GDesc{Z, pw3b, pb3, p_prev, P_bf, out_p, 512, 512, 512, 512, EP_TANH_ADD, 64};
        ga.d1 = ga.d0; ga.d2 = ga.d0; ga.s1 = 256; ga.s2 = 256;
        gemm_multi<<<dim3(256), blk, 0, stream>>>(ga);
    }

    // ---------- up: pm = P_bf @ up^T -> PM
    {
        GArgs ga;
        ga.d0 = GDesc{P_bf, upb, nullptr, nullptr, PM, nullptr, 512, 1024, 1024, 512, EP_NONE, 64};
        ga.d1 = ga.d0; ga.d2 = ga.d0; ga.s1 = 512; ga.s2 = 512;
        gemm_multi<<<dim3(512), blk, 0, stream>>>(ga);
    }

    mix_ln<<<8192, blk, 0, stream>>>(s_prev, G, PM, WM, oln_g, oln_b, out_s);
}